// Round 13
// baseline (105.484 us; speedup 1.0000x reference)
//
#include <hip/hip_runtime.h>
#include <math.h>

#define Bsz 8
#define Cch 256
#define Nsp 1024
#define NHd 4
#define QS  0.18033688011112042f   // 0.125 * log2(e)

using bf16x8  = __attribute__((ext_vector_type(8))) short;
using f32x4   = __attribute__((ext_vector_type(4))) float;
using ushort8 = __attribute__((ext_vector_type(8))) unsigned short;
#define MFMA(a,b,c) __builtin_amdgcn_mfma_f32_16x16x32_bf16(a,b,c,0,0,0)

__device__ inline unsigned short f2bf(float f) {
    unsigned int u = __float_as_uint(f);
    u = u + 0x7fffu + ((u >> 16) & 1u);   // RNE
    return (unsigned short)(u >> 16);
}
__device__ inline float bf2f(unsigned short u) {
    return __uint_as_float((unsigned int)u << 16);
}
__device__ inline unsigned int cvtpk(float lo, float hi) {
    unsigned int r;
    asm("v_cvt_pk_bf16_f32 %0, %1, %2" : "=v"(r) : "v"(lo), "v"(hi));
    return r;
}

// ---------- fused: weight f32->bf16 conversion + stage-1 GN reduction ----------
__global__ __launch_bounds__(256) void wconv_gn(const float* __restrict__ a, const float* __restrict__ b,
                                                const float* __restrict__ c, const float* __restrict__ d,
                                                unsigned short* __restrict__ o,
                                                const float* __restrict__ x,
                                                float* __restrict__ part) {
    if (blockIdx.x < 3072) {
        size_t i = (size_t)blockIdx.x * 256 + threadIdx.x;
        float v;
        if (i < 196608) v = a[i];
        else if (i < 262144) v = b[i - 196608];
        else if (i < 524288) v = c[i - 262144];
        else v = d[i - 524288];
        o[i] = f2bf(v);
        return;
    }
    int blk = blockIdx.x - 3072;
    int bb = blk >> 6;
    const float* xb = x + (size_t)bb * (Cch * Nsp) + (size_t)(blk & 63) * 4096;
    int t = threadIdx.x;
    float s = 0.f, s2 = 0.f;
    for (int i = t; i < 4096; i += 256) { float v = xb[i]; s += v; s2 += v * v; }
    __shared__ float sh[256], sh2[256];
    sh[t] = s; sh2[t] = s2; __syncthreads();
    for (int off = 128; off; off >>= 1) {
        if (t < off) { sh[t] += sh[t + off]; sh2[t] += sh2[t + off]; }
        __syncthreads();
    }
    if (t == 0) { part[blk * 2] = sh[0]; part[blk * 2 + 1] = sh2[0]; }
}

// ---------- LDS-staged MFMA GEMM (named-register W triple-buffer chain) ----------
// xmode 0: X from Xcl.  xmode 1: X = GN2(normalize) of Xcl using gnpart stats + gnw/gnb.
// xmode 2: X = split-KV combine of 2 Opart partials (Xcl) with lpart denoms (gnpart).
// xmode 3: X = GN1(normalize) of f32 channel-first x (via `res`), fused transpose
//          into the swizzled LDS layout (requires NTILE==32, kofs==0).
// epi 0: channel-last bf16 store (act 1: silu; act 3: qkv — q scaled QS, v row-major)
// epi 2: orm = bf16(res + gamma*(acc+bias)) channel-first, + x2cl bf16 CL copy,
//        + (sum,sumsq) partials
template<int K, int KL, int NFRAG>
__global__ __launch_bounds__(256, 4) void gemm_lds(
        const unsigned short* __restrict__ W,
        const unsigned short* __restrict__ Xcl,
        int epi, int act, int xmode,
        unsigned short* __restrict__ ocl, int Ocl, int ocol0,
        unsigned short* __restrict__ orm,
        float* __restrict__ pf, const float* __restrict__ res,
        unsigned short* __restrict__ x2cl,
        const float* __restrict__ gamma, const float* __restrict__ bias,
        float* __restrict__ part,
        const float* __restrict__ gnpart,
        const float* __restrict__ gnw, const float* __restrict__ gnb) {
    static_assert(KL == 256 && K == 256, "single-round K only");
    constexpr int NTILE = NFRAG * 16;
    constexpr int CPR = KL / 8;
    constexpr int TOTCH = NTILE * CPR;
    int b = blockIdx.z, nb = blockIdx.x, ob = blockIdx.y;
    int t = threadIdx.x, w = t >> 6, l = t & 63, lg = l >> 4, lm = l & 15;
    __shared__ unsigned short Xs[NTILE * KL];
    __shared__ float sgn[2];
    const unsigned short* Xb = Xcl + ((size_t)b * Nsp + nb * NTILE) * K;
    int o_base = ob * 256 + w * 64;
    const unsigned short* Wp = W + (size_t)(o_base + lm) * K + 8 * lg;
    int m8 = lm & 7;

    bf16x8 wA0, wA1, wA2, wA3, wB0, wB1, wB2, wB3, wC0, wC1, wC2, wC3;
    #define WL(d0, d1, d2, d3, ks_) do {                                   \
        d0 = *(const bf16x8*)(Wp + (size_t)(0)      + (ks_) * 32);         \
        d1 = *(const bf16x8*)(Wp + (size_t)16 * K   + (ks_) * 32);         \
        d2 = *(const bf16x8*)(Wp + (size_t)32 * K   + (ks_) * 32);         \
        d3 = *(const bf16x8*)(Wp + (size_t)48 * K   + (ks_) * 32);         \
    } while (0)
    // issue first two W-step loads before staging so they overlap it
    WL(wA0, wA1, wA2, wA3, 0);
    WL(wB0, wB1, wB2, wB3, 1);

    if (xmode == 0) {
        #pragma unroll
        for (int i = 0; i < TOTCH / 256; i++) {
            int c = i * 256 + t;
            int n = c / CPR, s = c % CPR;
            int gc = s ^ (n & 7);
            *(bf16x8*)&Xs[c * 8] = *(const bf16x8*)(Xb + (size_t)n * K + gc * 8);
        }
    } else if (xmode == 1) {
        if (t < 64) {
            float s = gnpart[(b * 64 + t) * 2], s2 = gnpart[(b * 64 + t) * 2 + 1];
            for (int m = 1; m < 64; m <<= 1) { s += __shfl_xor(s, m); s2 += __shfl_xor(s2, m); }
            if (t == 0) {
                float inv_n = 1.f / (Cch * Nsp);
                float mu = s * inv_n;
                float var = s2 * inv_n - mu * mu;
                sgn[0] = mu; sgn[1] = rsqrtf(var + 1e-5f);
            }
        }
        __syncthreads();
        float mu = sgn[0], rs = sgn[1];
        #pragma unroll
        for (int i = 0; i < TOTCH / 256; i++) {
            int c = i * 256 + t;
            int n = c / CPR, s = c % CPR;
            int gc = s ^ (n & 7);
            ushort8 xv = *(const ushort8*)(Xb + (size_t)n * K + gc * 8);
            f32x4 w0 = *(const f32x4*)(gnw + gc * 8);
            f32x4 w1 = *(const f32x4*)(gnw + gc * 8 + 4);
            f32x4 b0 = *(const f32x4*)(gnb + gc * 8);
            f32x4 b1 = *(const f32x4*)(gnb + gc * 8 + 4);
            ushort8 rr;
            #pragma unroll
            for (int j = 0; j < 4; j++) {
                rr[j]     = f2bf((bf2f(xv[j])     - mu) * rs * w0[j] + b0[j]);
                rr[4 + j] = f2bf((bf2f(xv[4 + j]) - mu) * rs * w1[j] + b1[j]);
            }
            *(ushort8*)&Xs[c * 8] = rr;
        }
    } else if (xmode == 2) {  // fused split-KV combine, 2 splits (Xcl = Opart, gnpart = lpart)
        const size_t SPO = (size_t)Bsz * Nsp * Cch;
        #pragma unroll
        for (int i = 0; i < TOTCH / 256; i++) {
            int c = i * 256 + t;
            int n = c / CPR, s = c % CPR;
            int gc = s ^ (n & 7);
            const unsigned short* p0 = Xb + (size_t)n * K + gc * 8;
            int h = gc >> 3;
            int gn = nb * NTILE + n;
            float a0[8] = {};
            float lsum = 0.f;
            #pragma unroll
            for (int sp = 0; sp < 2; sp++) {
                ushort8 ov = *(const ushort8*)(p0 + (size_t)sp * SPO);
                #pragma unroll
                for (int j = 0; j < 8; j++) a0[j] += bf2f(ov[j]);
                lsum += gnpart[(((size_t)sp * Bsz + b) * NHd + h) * Nsp + gn];
            }
            float inv = 1.f / lsum;
            ushort8 rr;
            #pragma unroll
            for (int j = 0; j < 8; j++) rr[j] = f2bf(a0[j] * inv);
            *(ushort8*)&Xs[c * 8] = rr;
        }
    } else {  // xmode == 3: GN1 from f32 channel-first x (res), fused transpose
        if (t < 64) {
            float s = gnpart[(b * 64 + t) * 2], s2 = gnpart[(b * 64 + t) * 2 + 1];
            for (int m = 1; m < 64; m <<= 1) { s += __shfl_xor(s, m); s2 += __shfl_xor(s2, m); }
            if (t == 0) {
                float inv_n = 1.f / (Cch * Nsp);
                float mu = s * inv_n;
                float var = s2 * inv_n - mu * mu;
                sgn[0] = mu; sgn[1] = rsqrtf(var + 1e-5f);
            }
        }
        __syncthreads();
        float mu = sgn[0], rs = sgn[1];
        int n = t & 31;
        #pragma unroll
        for (int i = 0; i < 4; i++) {
            int G = i * 8 + (t >> 5);                     // channel-group 0..31
            const float* xr = res + ((size_t)b * Cch + G * 8) * Nsp + (size_t)nb * NTILE + n;
            ushort8 rr;
            #pragma unroll
            for (int j = 0; j < 8; j++) {
                float val = xr[(size_t)j * Nsp];
                rr[j] = f2bf((val - mu) * rs * gnw[G * 8 + j] + gnb[G * 8 + j]);
            }
            int slot = G ^ (n & 7);
            *(ushort8*)&Xs[(n * 32 + slot) * 8] = rr;
        }
    }
    __syncthreads();

    f32x4 acc[4][NFRAG] = {};
    #define KS(w0_, w1_, w2_, w3_, ks_) do {                               \
        _Pragma("unroll")                                                  \
        for (int nf = 0; nf < NFRAG; nf++) {                               \
            int slot = ((ks_) * 4 + lg) ^ m8;                              \
            bf16x8 xf = *(const bf16x8*)&Xs[((nf * 16 + lm) * CPR + slot) * 8]; \
            acc[0][nf] = MFMA(w0_, xf, acc[0][nf]);                        \
            acc[1][nf] = MFMA(w1_, xf, acc[1][nf]);                        \
            acc[2][nf] = MFMA(w2_, xf, acc[2][nf]);                        \
            acc[3][nf] = MFMA(w3_, xf, acc[3][nf]);                        \
        }                                                                  \
    } while (0)
    WL(wC0, wC1, wC2, wC3, 2); KS(wA0, wA1, wA2, wA3, 0);
    WL(wA0, wA1, wA2, wA3, 3); KS(wB0, wB1, wB2, wB3, 1);
    WL(wB0, wB1, wB2, wB3, 4); KS(wC0, wC1, wC2, wC3, 2);
    WL(wC0, wC1, wC2, wC3, 5); KS(wA0, wA1, wA2, wA3, 3);
    WL(wA0, wA1, wA2, wA3, 6); KS(wB0, wB1, wB2, wB3, 4);
    WL(wB0, wB1, wB2, wB3, 7); KS(wC0, wC1, wC2, wC3, 5);
    KS(wA0, wA1, wA2, wA3, 6);
    KS(wB0, wB1, wB2, wB3, 7);
    #undef WL
    #undef KS

    if (epi == 0) {
        if (act == 3 && o_base >= 512) {          // v rows -> row-major [256][1024]
            #pragma unroll
            for (int nf = 0; nf < NFRAG; nf++) {
                int n = nb * NTILE + nf * 16 + lm;
                #pragma unroll
                for (int q = 0; q < 4; q++)
                    #pragma unroll
                    for (int r = 0; r < 4; r++) {
                        int o = o_base + q * 16 + 4 * lg + r - 512;
                        orm[((size_t)b * Cch + o) * Nsp + n] = f2bf(acc[q][nf][r]);
                    }
            }
        } else {
            float sc = (act == 3 && o_base < 256) ? QS : 1.f;
            #pragma unroll
            for (int nf = 0; nf < NFRAG; nf++) {
                int n = nb * NTILE + nf * 16 + lm;
                unsigned short* dst = ocl + ((size_t)b * Nsp + n) * Ocl + ocol0 + o_base + 4 * lg;
                #pragma unroll
                for (int q = 0; q < 4; q++) {
                    unsigned long long pk = 0;
                    #pragma unroll
                    for (int r = 0; r < 4; r++) {
                        int o = o_base + q * 16 + 4 * lg + r;
                        float v = acc[q][nf][r];
                        if (bias) v += bias[o];
                        if (act == 1) v = v / (1.f + __expf(-v));
                        else v *= sc;
                        pk |= (unsigned long long)f2bf(v) << (16 * r);
                    }
                    *(unsigned long long*)(dst + q * 16) = pk;
                }
            }
        }
    } else {  // epi == 2
        float g = gamma[0];
        float ps = 0.f, ps2 = 0.f;
        #pragma unroll
        for (int nf = 0; nf < NFRAG; nf++) {
            int n = nb * NTILE + nf * 16 + lm;
            unsigned short* cdst = x2cl + ((size_t)b * Nsp + n) * Cch + o_base + 4 * lg;
            #pragma unroll
            for (int q = 0; q < 4; q++) {
                unsigned long long pk = 0;
                #pragma unroll
                for (int r = 0; r < 4; r++) {
                    int o = o_base + q * 16 + 4 * lg + r;
                    float v = acc[q][nf][r];
                    if (bias) v += bias[o];
                    size_t idx = ((size_t)b * Cch + o) * Nsp + n;
                    float ov = res[idx] + g * v;
                    orm[idx] = f2bf(ov);            // x2 channel-first, bf16
                    ps += ov; ps2 += ov * ov;
                    pk |= (unsigned long long)f2bf(ov) << (16 * r);
                }
                *(unsigned long long*)(cdst + q * 16) = pk;
            }
        }
        float* rsh  = (float*)&Xs[0];
        float* rsh2 = rsh + 256;
        __syncthreads();
        rsh[t] = ps; rsh2[t] = ps2; __syncthreads();
        for (int off = 128; off; off >>= 1) {
            if (t < off) { rsh[t] += rsh[t + off]; rsh2[t] += rsh2[t + off]; }
            __syncthreads();
        }
        if (t == 0) {
            int slot = b * gridDim.x + nb;
            part[slot * 2] = rsh[0]; part[slot * 2 + 1] = rsh2[0];
        }
    }
}

// ---------- fused FFN: 1024 threads, bf16 x2 residual ----------
// grid (32, 1, 8). f1: single pass, 16 warps x 64 outs (12-name chain). f2: 16 warps
// x 16 outs, K=1024, 8-name W rotation with 6-step lookahead.
__global__ __launch_bounds__(1024, 2) void ffn_fused(
        const unsigned short* __restrict__ Wf1,
        const unsigned short* __restrict__ Wf2,
        const unsigned short* __restrict__ x2cl,
        const float* __restrict__ gnpart,
        const float* __restrict__ gnw, const float* __restrict__ gnb,
        const float* __restrict__ f1b, const float* __restrict__ f2b,
        const float* __restrict__ gamma,
        const unsigned short* __restrict__ x2, float* __restrict__ out) {
    int b = blockIdx.z, nb = blockIdx.x;
    int t = threadIdx.x, w = t >> 6, l = t & 63, lg = l >> 4, lm = l & 15;
    __shared__ unsigned short Xs[32 * 256];      // 16 KB staged GN2(x2cl)
    __shared__ unsigned short H[4][32 * 256];    // 64 KB hidden
    __shared__ float sgn[2];
    const unsigned short* Xb = x2cl + ((size_t)b * Nsp + nb * 32) * 256;
    int m8 = lm & 7;

    bf16x8 wA0, wA1, wA2, wA3, wB0, wB1, wB2, wB3, wC0, wC1, wC2, wC3;
    const unsigned short* Wp = Wf1 + (size_t)(w * 64 + lm) * 256 + 8 * lg;
    #define WL1(d0, d1, d2, d3, ks_) do {                                  \
        d0 = *(const bf16x8*)(Wp + (ks_) * 32);                            \
        d1 = *(const bf16x8*)(Wp + (size_t)16 * 256 + (ks_) * 32);         \
        d2 = *(const bf16x8*)(Wp + (size_t)32 * 256 + (ks_) * 32);         \
        d3 = *(const bf16x8*)(Wp + (size_t)48 * 256 + (ks_) * 32);         \
    } while (0)

    if (t < 64) {
        float s = gnpart[(b * 64 + t) * 2], s2 = gnpart[(b * 64 + t) * 2 + 1];
        for (int m = 1; m < 64; m <<= 1) { s += __shfl_xor(s, m); s2 += __shfl_xor(s2, m); }
        if (t == 0) {
            float inv_n = 1.f / (Cch * Nsp);
            float mu = s * inv_n;
            float var = s2 * inv_n - mu * mu;
            sgn[0] = mu; sgn[1] = rsqrtf(var + 1e-5f);
        }
    }
    WL1(wA0, wA1, wA2, wA3, 0);
    WL1(wB0, wB1, wB2, wB3, 1);
    __syncthreads();
    {
        float mu = sgn[0], rs = sgn[1];
        int c = t;                                    // 1024 chunks, one per thread
        int n = c >> 5, s = c & 31;
        int gc = s ^ (n & 7);
        ushort8 xv = *(const ushort8*)(Xb + (size_t)n * 256 + gc * 8);
        f32x4 w0 = *(const f32x4*)(gnw + gc * 8);
        f32x4 w1 = *(const f32x4*)(gnw + gc * 8 + 4);
        f32x4 b0 = *(const f32x4*)(gnb + gc * 8);
        f32x4 b1 = *(const f32x4*)(gnb + gc * 8 + 4);
        ushort8 rr;
        #pragma unroll
        for (int j = 0; j < 4; j++) {
            rr[j]     = f2bf((bf2f(xv[j])     - mu) * rs * w0[j] + b0[j]);
            rr[4 + j] = f2bf((bf2f(xv[4 + j]) - mu) * rs * w1[j] + b1[j]);
        }
        *(ushort8*)&Xs[c * 8] = rr;
    }
    __syncthreads();

    f32x4 acc[4][2];
    #pragma unroll
    for (int q = 0; q < 4; q++)
        #pragma unroll
        for (int nf = 0; nf < 2; nf++) acc[q][nf] = (f32x4){0.f, 0.f, 0.f, 0.f};
    #define KS1(w0_, w1_, w2_, w3_, ks_) do {                              \
        _Pragma("unroll")                                                  \
        for (int nf = 0; nf < 2; nf++) {                                   \
            int slot = ((ks_) * 4 + lg) ^ m8;                              \
            bf16x8 xf = *(const bf16x8*)&Xs[((nf * 16 + lm) * 32 + slot) * 8]; \
            acc[0][nf] = MFMA(w0_, xf, acc[0][nf]);                        \
            acc[1][nf] = MFMA(w1_, xf, acc[1][nf]);                        \
            acc[2][nf] = MFMA(w2_, xf, acc[2][nf]);                        \
            acc[3][nf] = MFMA(w3_, xf, acc[3][nf]);                        \
        }                                                                  \
    } while (0)
    WL1(wC0, wC1, wC2, wC3, 2); KS1(wA0, wA1, wA2, wA3, 0);
    WL1(wA0, wA1, wA2, wA3, 3); KS1(wB0, wB1, wB2, wB3, 1);
    WL1(wB0, wB1, wB2, wB3, 4); KS1(wC0, wC1, wC2, wC3, 2);
    WL1(wC0, wC1, wC2, wC3, 5); KS1(wA0, wA1, wA2, wA3, 3);
    WL1(wA0, wA1, wA2, wA3, 6); KS1(wB0, wB1, wB2, wB3, 4);
    WL1(wB0, wB1, wB2, wB3, 7); KS1(wC0, wC1, wC2, wC3, 5);
    KS1(wA0, wA1, wA2, wA3, 6);
    KS1(wB0, wB1, wB2, wB3, 7);
    #undef WL1
    #undef KS1

    // f2 prologue: 6 W loads in flight before the H barrier
    const unsigned short* Wp2 = Wf2 + (size_t)(w * 16 + lm) * 1024 + 8 * lg;
    bf16x8 fa, fb, fc, fd, fe, ff, fg, fh;
    #define WL2(d0, ks_) d0 = *(const bf16x8*)(Wp2 + (ks_) * 32)
    WL2(fa, 0); WL2(fb, 1); WL2(fc, 2); WL2(fd, 3); WL2(fe, 4); WL2(ff, 5);

    // f1 epilogue: silu + pack into swizzled H
    {
        int hb = w >> 2;
        #pragma unroll
        for (int nf = 0; nf < 2; nf++) {
            int n = nf * 16 + lm;
            #pragma unroll
            for (int q = 0; q < 4; q++) {
                unsigned long long pk = 0;
                #pragma unroll
                for (int r = 0; r < 4; r++) {
                    int o1 = w * 64 + q * 16 + 4 * lg + r;
                    float v = acc[q][nf][r] + f1b[o1];
                    v = v / (1.f + __expf(-v));
                    pk |= (unsigned long long)f2bf(v) << (16 * r);
                }
                int G = (w & 3) * 8 + q * 2 + (lg >> 1);
                int slot = G ^ (n & 7);
                *(unsigned long long*)&H[hb][(n * 32 + slot) * 8 + 4 * (lg & 1)] = pk;
            }
        }
    }
    __syncthreads();

    f32x4 ac2[2] = {};
    #define KS2(e0, g_) do {                                               \
        int slot = (((g_) & 7) * 4 + lg) ^ m8;                             \
        const unsigned short* Hp = H[(g_) >> 3];                           \
        _Pragma("unroll")                                                  \
        for (int nf = 0; nf < 2; nf++) {                                   \
            bf16x8 xf = *(const bf16x8*)&Hp[((nf * 16 + lm) * 32 + slot) * 8]; \
            ac2[nf] = MFMA(e0, xf, ac2[nf]);                               \
        }                                                                  \
    } while (0)
    // 8-name rotation, 6-step lookahead
    WL2(fg, 6);  KS2(fa, 0);
    WL2(fh, 7);  KS2(fb, 1);
    WL2(fa, 8);  KS2(fc, 2);
    WL2(fb, 9);  KS2(fd, 3);
    WL2(fc, 10); KS2(fe, 4);
    WL2(fd, 11); KS2(ff, 5);
    WL2(fe, 12); KS2(fg, 6);
    WL2(ff, 13); KS2(fh, 7);
    WL2(fg, 14); KS2(fa, 8);
    WL2(fh, 15); KS2(fb, 9);
    WL2(fa, 16); KS2(fc, 10);
    WL2(fb, 17); KS2(fd, 11);
    WL2(fc, 18); KS2(fe, 12);
    WL2(fd, 19); KS2(ff, 13);
    WL2(fe, 20); KS2(fg, 14);
    WL2(ff, 21); KS2(fh, 15);
    WL2(fg, 22); KS2(fa, 16);
    WL2(fh, 23); KS2(fb, 17);
    WL2(fa, 24); KS2(fc, 18);
    WL2(fb, 25); KS2(fd, 19);
    WL2(fc, 26); KS2(fe, 20);
    WL2(fd, 27); KS2(ff, 21);
    WL2(fe, 28); KS2(fg, 22);
    WL2(ff, 29); KS2(fh, 23);
    WL2(fg, 30); KS2(fa, 24);
    WL2(fh, 31); KS2(fb, 25);
    KS2(fc, 26);
    KS2(fd, 27);
    KS2(fe, 28);
    KS2(ff, 29);
    KS2(fg, 30);
    KS2(fh, 31);
    #undef WL2
    #undef KS2

    float gm = gamma[0];
    #pragma unroll
    for (int nf = 0; nf < 2; nf++) {
        int n = nb * 32 + nf * 16 + lm;
        #pragma unroll
        for (int r = 0; r < 4; r++) {
            int o = w * 16 + 4 * lg + r;
            size_t idx = ((size_t)b * Cch + o) * Nsp + n;
            out[idx] = bf2f(x2[idx]) + gm * (ac2[nf][r] + f2b[o]);
        }
    }
}

// ---------- attention v11: 16 q-rows/warp, 1024 blocks (4/CU), sp=2, 3-buffer KV ----------
__global__ __launch_bounds__(256) void attn_mfma8(const unsigned short* __restrict__ qk,
                                                  const unsigned short* __restrict__ v,
                                                  unsigned short* __restrict__ Opart,
                                                  float* __restrict__ lpart) {
    int L = blockIdx.x;
    int xcd = L & 7, jj = L >> 3;            // 1024 blocks: 8 XCDs x 128
    int g = xcd * 4 + (jj >> 5);             // (b,h) 0..31
    int m = jj & 31;                         // (ib,sp) 0..31
    int h = g & 3, b = g >> 2;
    int ib = m & 15, sp = m >> 4;            // ib 0..15, sp {0,1}
    int t = threadIdx.x, w = t >> 6, l = t & 63, lg = l >> 4, lm = l & 15;
    __shared__ unsigned short KVs[3][4096];
    __shared__ unsigned short P[4][16][36];
    int i0 = ib * 64 + w * 16;
    int j0 = sp * 512;
    const unsigned short* qb = qk + ((size_t)b * Nsp + i0 + lm) * 512 + h * 64 + 8 * lg;
    bf16x8 qf00 = *(const bf16x8*)(qb);
    bf16x8 qf01 = *(const bf16x8*)(qb + 32);

    const unsigned short *gs0, *gs1;
    int lo0, lo1;
    size_t gstep;
    if (t < 128) {
        int c = 2 * t;
        int r = c >> 3, s = c & 7, swr = r & 7;
        const unsigned short* rowp = qk + ((size_t)b * Nsp + j0 + r) * 512 + 256 + h * 64;
        gs0 = rowp + ((s ^ swr) * 8);
        gs1 = rowp + (((s + 1) ^ swr) * 8);
        lo0 = c * 8; lo1 = lo0 + 8;
        gstep = (size_t)32 * 512;
    } else {
        int c = 2 * (t - 128);
        int d = c >> 2, s = c & 3, swd = d & 3;
        const unsigned short* rowp = v + ((size_t)b * Cch + h * 64 + d) * Nsp + j0;
        gs0 = rowp + ((s ^ swd) * 8);
        gs1 = rowp + (((s + 1) ^ swd) * 8);
        lo0 = 2048 + c * 8; lo1 = lo0 + 8;
        gstep = 32;
    }
    int cA = (lg ^ (lm & 7)) * 8;
    int cB = ((4 + lg) ^ (lm & 7)) * 8;
    int cV = (lg ^ (lm & 3)) * 8;

    f32x4 O00 = {}, O01 = {}, O02 = {}, O03 = {};
    float ls0 = 0.f;
    bf16x8 sg0, sg1;

    #define ISSUE(tile) do { sg0 = *(const bf16x8*)(gs0 + (size_t)(tile) * gstep); \
                             sg1 = *(const bf16x8*)(gs1 + (size_t)(tile) * gstep); } while (0)
    #define WRITE(bu) do { *(bf16x8*)&KVs[bu][lo0] = sg0; \
                           *(bf16x8*)&KVs[bu][lo1] = sg1; } while (0)
    #define QKC8(bu) do {                                                         \
        const unsigned short* Ka = KVs[bu] + lm * 64;                             \
        const unsigned short* Kc = KVs[bu] + (16 + lm) * 64;                      \
        bf16x8 k00 = *(const bf16x8*)(Ka + cA);                                   \
        bf16x8 k01 = *(const bf16x8*)(Ka + cB);                                   \
        bf16x8 k10 = *(const bf16x8*)(Kc + cA);                                   \
        bf16x8 k11 = *(const bf16x8*)(Kc + cB);                                   \
        f32x4 s00 = {}, s10 = {};                                                 \
        s00 = MFMA(k00, qf00, s00); s00 = MFMA(k01, qf01, s00);                   \
        s10 = MFMA(k10, qf00, s10); s10 = MFMA(k11, qf01, s10);                   \
        float p0, p1, p2, p3; uint2 pk;                                           \
        p0 = exp2f(s00[0]); p1 = exp2f(s00[1]); p2 = exp2f(s00[2]); p3 = exp2f(s00[3]); \
        ls0 += (p0 + p1) + (p2 + p3);                                             \
        pk.x = cvtpk(p0, p1); pk.y = cvtpk(p2, p3);                               \
        *(uint2*)&P[w][lm][4 * lg] = pk;                                          \
        p0 = exp2f(s10[0]); p1 = exp2f(s10[1]); p2 = exp2f(s10[2]); p3 = exp2f(s10[3]); \
        ls0 += (p0 + p1) + (p2 + p3);                                             \
        pk.x = cvtpk(p0, p1); pk.y = cvtpk(p2, p3);                               \
        *(uint2*)&P[w][lm][16 + 4 * lg] = pk;                                     \
    } while (0)
    #define PVC8(bu) do {                                                         \
        bf16x8 pa0 = *(const bf16x8*)&P[w][lm][8 * lg];                           \
        const unsigned short* Vl = KVs[bu] + 2048;                                \
        bf16x8 v0 = *(const bf16x8*)(Vl + lm * 32 + cV);                          \
        bf16x8 v1 = *(const bf16x8*)(Vl + (16 + lm) * 32 + cV);                   \
        bf16x8 v2 = *(const bf16x8*)(Vl + (32 + lm) * 32 + cV);                   \
        bf16x8 v3 = *(const bf16x8*)(Vl + (48 + lm) * 32 + cV);                   \
        O00 = MFMA(v0, pa0, O00);                                                 \
        O01 = MFMA(v1, pa0, O01);                                                 \
        O02 = MFMA(v2, pa0, O02);                                                 \
        O03 = MFMA(v3, pa0, O03);                                                 \
    } while (0)

    // prologue: tile0 staged; tile1 staged into buf1 while QK(tile0) computes
    ISSUE(0); WRITE(0); __syncthreads();
    ISSUE(1);
    QKC8(0);             // P <- tile0
    WRITE(1);
    __syncthreads();
    // steady state: 1 barrier per tile. At iter tt: QK reads buf tt%3,
    // PV reads buf (tt-1)%3, WRITE targets buf (tt+1)%3 (== (tt-2)%3, whose
    // last reader finished before the previous barrier).
    #pragma unroll
    for (int tt = 1; tt < 16; tt++) {
        if (tt < 15) ISSUE(tt + 1);
        PVC8((tt - 1) % 3);   // reads P (tile tt-1) before QK overwrites it
        QKC8(tt % 3);         // P <- tile tt
        if (tt < 15) WRITE((tt + 1) % 3);
        __syncthreads();
    }
    PVC8(0);                  // tile 15 (15 % 3 == 0)
    #undef ISSUE
    #undef WRITE
    #undef QKC8
    #undef PVC8

    ls0 += __shfl_xor(ls0, 16); ls0 += __shfl_xor(ls0, 32);
    if (lg == 0) {
        float* lp = lpart + (((size_t)sp * Bsz + b) * NHd + h) * Nsp + i0 + lm;
        lp[0] = ls0;
    }
    unsigned short* ob0 = Opart + (((size_t)sp * Bsz + b) * Nsp + i0 + lm) * Cch + h * 64 + 4 * lg;
    uint2 pk;
    #define STO(dt, Oa) \
        pk.x = cvtpk(Oa[0], Oa[1]); pk.y = cvtpk(Oa[2], Oa[3]); \
        *(uint2*)(ob0 + dt * 16) = pk;
    STO(0, O00) STO(1, O01) STO(2, O02) STO(3, O03)
    #undef STO
}

extern "C" void kernel_launch(void* const* d_in, const int* in_sizes, int n_in,
                              void* d_out, int out_size, void* d_ws, size_t ws_size,
                              hipStream_t stream) {
    const float* x      = (const float*)d_in[0];
    const float* qkv_w  = (const float*)d_in[1];
    const float* uh_w   = (const float*)d_in[2];
    const float* uh_b   = (const float*)d_in[3];
    const float* n1_w   = (const float*)d_in[4];
    const float* n1_b   = (const float*)d_in[5];
    const float* n2_w   = (const float*)d_in[6];
    const float* n2_b   = (const float*)d_in[7];
    const float* f1_w   = (const float*)d_in[8];
    const float* f1_b   = (const float*)d_in[9];
    const float* f2_w   = (const float*)d_in[10];
    const float* f2_b   = (const float*)d_in[11];
    const float* g_attn = (const float*)d_in[12];
    const float* g_ffn  = (const float*)d_in[13];
    float* out = (float*)d_out;
    char* ws = (char*)d_ws;

    float*          part1   = (float*)(ws + 1024);
    float*          part2   = (float*)(ws + 5120);
    unsigned short* wbf     = (unsigned short*)(ws + 16384);
    float*          lpart   = (float*)(ws + 2097152);
    unsigned short* qk_cl   = (unsigned short*)(ws + 6291456);
    unsigned short* vbuf    = (unsigned short*)(ws + 14680064);
    unsigned short* x2cl    = (unsigned short*)(ws + 14680064);  // reuses vbuf after attn
    unsigned short* Opart   = (unsigned short*)(ws + 23068672);  // 2 splits x 4MB
    unsigned short* x2rm    = (unsigned short*)(ws + 50331648);  // x2, channel-first bf16

    unsigned short* wbf_qkv = wbf;
    unsigned short* wbf_uh  = wbf + 196608;
    unsigned short* wbf_f1  = wbf + 262144;
    unsigned short* wbf_f2  = wbf + 524288;

    wconv_gn<<<3584, 256, 0, stream>>>(qkv_w, uh_w, f1_w, f2_w, wbf, x, part1);

    // --- attention branch (GN1 fused into qkv staging, xmode=3) ---
    gemm_lds<256, 256, 2><<<dim3(32, 3, Bsz), 256, 0, stream>>>(wbf_qkv,
        (const unsigned short*)x, 0, 3, 3,
        qk_cl, 512, 0, vbuf, nullptr, x, nullptr, nullptr, nullptr, nullptr,
        part1, n1_w, n1_b);
    attn_mfma8<<<1024, 256, 0, stream>>>(qk_cl, vbuf, Opart, lpart);
    // uh GEMM: fused 2-split combine (xmode=2); x2 stored bf16 CF (orm) + bf16 CL (x2cl)
    gemm_lds<256, 256, 1><<<dim3(64, 1, Bsz), 256, 0, stream>>>(wbf_uh, Opart, 2, 0, 2,
        nullptr, 0, 0, x2rm, nullptr, x, x2cl, g_attn, uh_b, part2,
        lpart, nullptr, nullptr);

    // --- FFN branch: single fused kernel, bf16 x2 residual ---
    ffn_fused<<<dim3(32, 1, Bsz), 1024, 0, stream>>>(wbf_f1, wbf_f2, x2cl,
        part2, n2_w, n2_b, f1_b, f2_b, g_ffn, x2rm, out);
}

// Round 14
// 104.844 us; speedup vs baseline: 1.0061x; 1.0061x over previous
//
#include <hip/hip_runtime.h>
#include <math.h>

#define Bsz 8
#define Cch 256
#define Nsp 1024
#define NHd 4
#define QS  0.18033688011112042f   // 0.125 * log2(e)

using bf16x8  = __attribute__((ext_vector_type(8))) short;
using f32x4   = __attribute__((ext_vector_type(4))) float;
using ushort8 = __attribute__((ext_vector_type(8))) unsigned short;
#define MFMA(a,b,c) __builtin_amdgcn_mfma_f32_16x16x32_bf16(a,b,c,0,0,0)

__device__ inline unsigned short f2bf(float f) {
    unsigned int u = __float_as_uint(f);
    u = u + 0x7fffu + ((u >> 16) & 1u);   // RNE
    return (unsigned short)(u >> 16);
}
__device__ inline float bf2f(unsigned short u) {
    return __uint_as_float((unsigned int)u << 16);
}
__device__ inline unsigned int cvtpk(float lo, float hi) {
    unsigned int r;
    asm("v_cvt_pk_bf16_f32 %0, %1, %2" : "=v"(r) : "v"(lo), "v"(hi));
    return r;
}

// ---------- fused: weight f32->bf16 conversion + stage-1 GN reduction ----------
__global__ __launch_bounds__(256) void wconv_gn(const float* __restrict__ a, const float* __restrict__ b,
                                                const float* __restrict__ c, const float* __restrict__ d,
                                                unsigned short* __restrict__ o,
                                                const float* __restrict__ x,
                                                float* __restrict__ part) {
    if (blockIdx.x < 3072) {
        size_t i = (size_t)blockIdx.x * 256 + threadIdx.x;
        float v;
        if (i < 196608) v = a[i];
        else if (i < 262144) v = b[i - 196608];
        else if (i < 524288) v = c[i - 262144];
        else v = d[i - 524288];
        o[i] = f2bf(v);
        return;
    }
    int blk = blockIdx.x - 3072;
    int bb = blk >> 6;
    const float* xb = x + (size_t)bb * (Cch * Nsp) + (size_t)(blk & 63) * 4096;
    int t = threadIdx.x;
    float s = 0.f, s2 = 0.f;
    for (int i = t; i < 4096; i += 256) { float v = xb[i]; s += v; s2 += v * v; }
    __shared__ float sh[256], sh2[256];
    sh[t] = s; sh2[t] = s2; __syncthreads();
    for (int off = 128; off; off >>= 1) {
        if (t < off) { sh[t] += sh[t + off]; sh2[t] += sh2[t + off]; }
        __syncthreads();
    }
    if (t == 0) { part[blk * 2] = sh[0]; part[blk * 2 + 1] = sh2[0]; }
}

// ---------- LDS-staged MFMA GEMM (named-register W triple-buffer chain) ----------
// xmode 0: X from Xcl.  xmode 1: X = GN2(normalize) of Xcl using gnpart stats + gnw/gnb.
// xmode 2: X = split-KV combine of 2 Opart partials (Xcl) with lpart denoms (gnpart).
// xmode 3: X = GN1(normalize) of f32 channel-first x (via `res`), fused transpose
//          into the swizzled LDS layout (requires NTILE==32, kofs==0).
// epi 0: channel-last bf16 store (act 1: silu; act 3: qkv — q scaled QS, v row-major)
// epi 2: orm = bf16(res + gamma*(acc+bias)) channel-first, + x2cl bf16 CL copy,
//        + (sum,sumsq) partials
template<int K, int KL, int NFRAG>
__global__ __launch_bounds__(256, 4) void gemm_lds(
        const unsigned short* __restrict__ W,
        const unsigned short* __restrict__ Xcl,
        int epi, int act, int xmode,
        unsigned short* __restrict__ ocl, int Ocl, int ocol0,
        unsigned short* __restrict__ orm,
        float* __restrict__ pf, const float* __restrict__ res,
        unsigned short* __restrict__ x2cl,
        const float* __restrict__ gamma, const float* __restrict__ bias,
        float* __restrict__ part,
        const float* __restrict__ gnpart,
        const float* __restrict__ gnw, const float* __restrict__ gnb) {
    static_assert(KL == 256 && K == 256, "single-round K only");
    constexpr int NTILE = NFRAG * 16;
    constexpr int CPR = KL / 8;
    constexpr int TOTCH = NTILE * CPR;
    int b = blockIdx.z, nb = blockIdx.x, ob = blockIdx.y;
    int t = threadIdx.x, w = t >> 6, l = t & 63, lg = l >> 4, lm = l & 15;
    __shared__ unsigned short Xs[NTILE * KL];
    __shared__ float sgn[2];
    const unsigned short* Xb = Xcl + ((size_t)b * Nsp + nb * NTILE) * K;
    int o_base = ob * 256 + w * 64;
    const unsigned short* Wp = W + (size_t)(o_base + lm) * K + 8 * lg;
    int m8 = lm & 7;

    bf16x8 wA0, wA1, wA2, wA3, wB0, wB1, wB2, wB3, wC0, wC1, wC2, wC3;
    #define WL(d0, d1, d2, d3, ks_) do {                                   \
        d0 = *(const bf16x8*)(Wp + (size_t)(0)      + (ks_) * 32);         \
        d1 = *(const bf16x8*)(Wp + (size_t)16 * K   + (ks_) * 32);         \
        d2 = *(const bf16x8*)(Wp + (size_t)32 * K   + (ks_) * 32);         \
        d3 = *(const bf16x8*)(Wp + (size_t)48 * K   + (ks_) * 32);         \
    } while (0)
    // issue first two W-step loads before staging so they overlap it
    WL(wA0, wA1, wA2, wA3, 0);
    WL(wB0, wB1, wB2, wB3, 1);

    if (xmode == 0) {
        #pragma unroll
        for (int i = 0; i < TOTCH / 256; i++) {
            int c = i * 256 + t;
            int n = c / CPR, s = c % CPR;
            int gc = s ^ (n & 7);
            *(bf16x8*)&Xs[c * 8] = *(const bf16x8*)(Xb + (size_t)n * K + gc * 8);
        }
    } else if (xmode == 1) {
        if (t < 64) {
            float s = gnpart[(b * 64 + t) * 2], s2 = gnpart[(b * 64 + t) * 2 + 1];
            for (int m = 1; m < 64; m <<= 1) { s += __shfl_xor(s, m); s2 += __shfl_xor(s2, m); }
            if (t == 0) {
                float inv_n = 1.f / (Cch * Nsp);
                float mu = s * inv_n;
                float var = s2 * inv_n - mu * mu;
                sgn[0] = mu; sgn[1] = rsqrtf(var + 1e-5f);
            }
        }
        __syncthreads();
        float mu = sgn[0], rs = sgn[1];
        #pragma unroll
        for (int i = 0; i < TOTCH / 256; i++) {
            int c = i * 256 + t;
            int n = c / CPR, s = c % CPR;
            int gc = s ^ (n & 7);
            ushort8 xv = *(const ushort8*)(Xb + (size_t)n * K + gc * 8);
            f32x4 w0 = *(const f32x4*)(gnw + gc * 8);
            f32x4 w1 = *(const f32x4*)(gnw + gc * 8 + 4);
            f32x4 b0 = *(const f32x4*)(gnb + gc * 8);
            f32x4 b1 = *(const f32x4*)(gnb + gc * 8 + 4);
            ushort8 rr;
            #pragma unroll
            for (int j = 0; j < 4; j++) {
                rr[j]     = f2bf((bf2f(xv[j])     - mu) * rs * w0[j] + b0[j]);
                rr[4 + j] = f2bf((bf2f(xv[4 + j]) - mu) * rs * w1[j] + b1[j]);
            }
            *(ushort8*)&Xs[c * 8] = rr;
        }
    } else if (xmode == 2) {  // fused split-KV combine, 2 splits (Xcl = Opart, gnpart = lpart)
        const size_t SPO = (size_t)Bsz * Nsp * Cch;
        #pragma unroll
        for (int i = 0; i < TOTCH / 256; i++) {
            int c = i * 256 + t;
            int n = c / CPR, s = c % CPR;
            int gc = s ^ (n & 7);
            const unsigned short* p0 = Xb + (size_t)n * K + gc * 8;
            int h = gc >> 3;
            int gn = nb * NTILE + n;
            float a0[8] = {};
            float lsum = 0.f;
            #pragma unroll
            for (int sp = 0; sp < 2; sp++) {
                ushort8 ov = *(const ushort8*)(p0 + (size_t)sp * SPO);
                #pragma unroll
                for (int j = 0; j < 8; j++) a0[j] += bf2f(ov[j]);
                lsum += gnpart[(((size_t)sp * Bsz + b) * NHd + h) * Nsp + gn];
            }
            float inv = 1.f / lsum;
            ushort8 rr;
            #pragma unroll
            for (int j = 0; j < 8; j++) rr[j] = f2bf(a0[j] * inv);
            *(ushort8*)&Xs[c * 8] = rr;
        }
    } else {  // xmode == 3: GN1 from f32 channel-first x (res), fused transpose
        if (t < 64) {
            float s = gnpart[(b * 64 + t) * 2], s2 = gnpart[(b * 64 + t) * 2 + 1];
            for (int m = 1; m < 64; m <<= 1) { s += __shfl_xor(s, m); s2 += __shfl_xor(s2, m); }
            if (t == 0) {
                float inv_n = 1.f / (Cch * Nsp);
                float mu = s * inv_n;
                float var = s2 * inv_n - mu * mu;
                sgn[0] = mu; sgn[1] = rsqrtf(var + 1e-5f);
            }
        }
        __syncthreads();
        float mu = sgn[0], rs = sgn[1];
        int n = t & 31;
        #pragma unroll
        for (int i = 0; i < 4; i++) {
            int G = i * 8 + (t >> 5);                     // channel-group 0..31
            const float* xr = res + ((size_t)b * Cch + G * 8) * Nsp + (size_t)nb * NTILE + n;
            ushort8 rr;
            #pragma unroll
            for (int j = 0; j < 8; j++) {
                float val = xr[(size_t)j * Nsp];
                rr[j] = f2bf((val - mu) * rs * gnw[G * 8 + j] + gnb[G * 8 + j]);
            }
            int slot = G ^ (n & 7);
            *(ushort8*)&Xs[(n * 32 + slot) * 8] = rr;
        }
    }
    __syncthreads();

    f32x4 acc[4][NFRAG] = {};
    #define KS(w0_, w1_, w2_, w3_, ks_) do {                               \
        _Pragma("unroll")                                                  \
        for (int nf = 0; nf < NFRAG; nf++) {                               \
            int slot = ((ks_) * 4 + lg) ^ m8;                              \
            bf16x8 xf = *(const bf16x8*)&Xs[((nf * 16 + lm) * CPR + slot) * 8]; \
            acc[0][nf] = MFMA(w0_, xf, acc[0][nf]);                        \
            acc[1][nf] = MFMA(w1_, xf, acc[1][nf]);                        \
            acc[2][nf] = MFMA(w2_, xf, acc[2][nf]);                        \
            acc[3][nf] = MFMA(w3_, xf, acc[3][nf]);                        \
        }                                                                  \
    } while (0)
    WL(wC0, wC1, wC2, wC3, 2); KS(wA0, wA1, wA2, wA3, 0);
    WL(wA0, wA1, wA2, wA3, 3); KS(wB0, wB1, wB2, wB3, 1);
    WL(wB0, wB1, wB2, wB3, 4); KS(wC0, wC1, wC2, wC3, 2);
    WL(wC0, wC1, wC2, wC3, 5); KS(wA0, wA1, wA2, wA3, 3);
    WL(wA0, wA1, wA2, wA3, 6); KS(wB0, wB1, wB2, wB3, 4);
    WL(wB0, wB1, wB2, wB3, 7); KS(wC0, wC1, wC2, wC3, 5);
    KS(wA0, wA1, wA2, wA3, 6);
    KS(wB0, wB1, wB2, wB3, 7);
    #undef WL
    #undef KS

    if (epi == 0) {
        if (act == 3 && o_base >= 512) {          // v rows -> row-major [256][1024]
            #pragma unroll
            for (int nf = 0; nf < NFRAG; nf++) {
                int n = nb * NTILE + nf * 16 + lm;
                #pragma unroll
                for (int q = 0; q < 4; q++)
                    #pragma unroll
                    for (int r = 0; r < 4; r++) {
                        int o = o_base + q * 16 + 4 * lg + r - 512;
                        orm[((size_t)b * Cch + o) * Nsp + n] = f2bf(acc[q][nf][r]);
                    }
            }
        } else {
            float sc = (act == 3 && o_base < 256) ? QS : 1.f;
            #pragma unroll
            for (int nf = 0; nf < NFRAG; nf++) {
                int n = nb * NTILE + nf * 16 + lm;
                unsigned short* dst = ocl + ((size_t)b * Nsp + n) * Ocl + ocol0 + o_base + 4 * lg;
                #pragma unroll
                for (int q = 0; q < 4; q++) {
                    unsigned long long pk = 0;
                    #pragma unroll
                    for (int r = 0; r < 4; r++) {
                        int o = o_base + q * 16 + 4 * lg + r;
                        float v = acc[q][nf][r];
                        if (bias) v += bias[o];
                        if (act == 1) v = v / (1.f + __expf(-v));
                        else v *= sc;
                        pk |= (unsigned long long)f2bf(v) << (16 * r);
                    }
                    *(unsigned long long*)(dst + q * 16) = pk;
                }
            }
        }
    } else {  // epi == 2
        float g = gamma[0];
        float ps = 0.f, ps2 = 0.f;
        #pragma unroll
        for (int nf = 0; nf < NFRAG; nf++) {
            int n = nb * NTILE + nf * 16 + lm;
            unsigned short* cdst = x2cl + ((size_t)b * Nsp + n) * Cch + o_base + 4 * lg;
            #pragma unroll
            for (int q = 0; q < 4; q++) {
                unsigned long long pk = 0;
                #pragma unroll
                for (int r = 0; r < 4; r++) {
                    int o = o_base + q * 16 + 4 * lg + r;
                    float v = acc[q][nf][r];
                    if (bias) v += bias[o];
                    size_t idx = ((size_t)b * Cch + o) * Nsp + n;
                    float ov = res[idx] + g * v;
                    orm[idx] = f2bf(ov);            // x2 channel-first, bf16
                    ps += ov; ps2 += ov * ov;
                    pk |= (unsigned long long)f2bf(ov) << (16 * r);
                }
                *(unsigned long long*)(cdst + q * 16) = pk;
            }
        }
        float* rsh  = (float*)&Xs[0];
        float* rsh2 = rsh + 256;
        __syncthreads();
        rsh[t] = ps; rsh2[t] = ps2; __syncthreads();
        for (int off = 128; off; off >>= 1) {
            if (t < off) { rsh[t] += rsh[t + off]; rsh2[t] += rsh2[t + off]; }
            __syncthreads();
        }
        if (t == 0) {
            int slot = b * gridDim.x + nb;
            part[slot * 2] = rsh[0]; part[slot * 2 + 1] = rsh2[0];
        }
    }
}

// ---------- fused FFN: 1024 threads, bf16 x2 residual ----------
// grid (32, 1, 8). f1: single pass, 16 warps x 64 outs (12-name chain). f2: 16 warps
// x 16 outs, K=1024, 8-name W rotation with 6-step lookahead.
__global__ __launch_bounds__(1024, 2) void ffn_fused(
        const unsigned short* __restrict__ Wf1,
        const unsigned short* __restrict__ Wf2,
        const unsigned short* __restrict__ x2cl,
        const float* __restrict__ gnpart,
        const float* __restrict__ gnw, const float* __restrict__ gnb,
        const float* __restrict__ f1b, const float* __restrict__ f2b,
        const float* __restrict__ gamma,
        const unsigned short* __restrict__ x2, float* __restrict__ out) {
    int b = blockIdx.z, nb = blockIdx.x;
    int t = threadIdx.x, w = t >> 6, l = t & 63, lg = l >> 4, lm = l & 15;
    __shared__ unsigned short Xs[32 * 256];      // 16 KB staged GN2(x2cl)
    __shared__ unsigned short H[4][32 * 256];    // 64 KB hidden
    __shared__ float sgn[2];
    const unsigned short* Xb = x2cl + ((size_t)b * Nsp + nb * 32) * 256;
    int m8 = lm & 7;

    bf16x8 wA0, wA1, wA2, wA3, wB0, wB1, wB2, wB3, wC0, wC1, wC2, wC3;
    const unsigned short* Wp = Wf1 + (size_t)(w * 64 + lm) * 256 + 8 * lg;
    #define WL1(d0, d1, d2, d3, ks_) do {                                  \
        d0 = *(const bf16x8*)(Wp + (ks_) * 32);                            \
        d1 = *(const bf16x8*)(Wp + (size_t)16 * 256 + (ks_) * 32);         \
        d2 = *(const bf16x8*)(Wp + (size_t)32 * 256 + (ks_) * 32);         \
        d3 = *(const bf16x8*)(Wp + (size_t)48 * 256 + (ks_) * 32);         \
    } while (0)

    if (t < 64) {
        float s = gnpart[(b * 64 + t) * 2], s2 = gnpart[(b * 64 + t) * 2 + 1];
        for (int m = 1; m < 64; m <<= 1) { s += __shfl_xor(s, m); s2 += __shfl_xor(s2, m); }
        if (t == 0) {
            float inv_n = 1.f / (Cch * Nsp);
            float mu = s * inv_n;
            float var = s2 * inv_n - mu * mu;
            sgn[0] = mu; sgn[1] = rsqrtf(var + 1e-5f);
        }
    }
    WL1(wA0, wA1, wA2, wA3, 0);
    WL1(wB0, wB1, wB2, wB3, 1);
    __syncthreads();
    {
        float mu = sgn[0], rs = sgn[1];
        int c = t;                                    // 1024 chunks, one per thread
        int n = c >> 5, s = c & 31;
        int gc = s ^ (n & 7);
        ushort8 xv = *(const ushort8*)(Xb + (size_t)n * 256 + gc * 8);
        f32x4 w0 = *(const f32x4*)(gnw + gc * 8);
        f32x4 w1 = *(const f32x4*)(gnw + gc * 8 + 4);
        f32x4 b0 = *(const f32x4*)(gnb + gc * 8);
        f32x4 b1 = *(const f32x4*)(gnb + gc * 8 + 4);
        ushort8 rr;
        #pragma unroll
        for (int j = 0; j < 4; j++) {
            rr[j]     = f2bf((bf2f(xv[j])     - mu) * rs * w0[j] + b0[j]);
            rr[4 + j] = f2bf((bf2f(xv[4 + j]) - mu) * rs * w1[j] + b1[j]);
        }
        *(ushort8*)&Xs[c * 8] = rr;
    }
    __syncthreads();

    f32x4 acc[4][2];
    #pragma unroll
    for (int q = 0; q < 4; q++)
        #pragma unroll
        for (int nf = 0; nf < 2; nf++) acc[q][nf] = (f32x4){0.f, 0.f, 0.f, 0.f};
    #define KS1(w0_, w1_, w2_, w3_, ks_) do {                              \
        _Pragma("unroll")                                                  \
        for (int nf = 0; nf < 2; nf++) {                                   \
            int slot = ((ks_) * 4 + lg) ^ m8;                              \
            bf16x8 xf = *(const bf16x8*)&Xs[((nf * 16 + lm) * 32 + slot) * 8]; \
            acc[0][nf] = MFMA(w0_, xf, acc[0][nf]);                        \
            acc[1][nf] = MFMA(w1_, xf, acc[1][nf]);                        \
            acc[2][nf] = MFMA(w2_, xf, acc[2][nf]);                        \
            acc[3][nf] = MFMA(w3_, xf, acc[3][nf]);                        \
        }                                                                  \
    } while (0)
    WL1(wC0, wC1, wC2, wC3, 2); KS1(wA0, wA1, wA2, wA3, 0);
    WL1(wA0, wA1, wA2, wA3, 3); KS1(wB0, wB1, wB2, wB3, 1);
    WL1(wB0, wB1, wB2, wB3, 4); KS1(wC0, wC1, wC2, wC3, 2);
    WL1(wC0, wC1, wC2, wC3, 5); KS1(wA0, wA1, wA2, wA3, 3);
    WL1(wA0, wA1, wA2, wA3, 6); KS1(wB0, wB1, wB2, wB3, 4);
    WL1(wB0, wB1, wB2, wB3, 7); KS1(wC0, wC1, wC2, wC3, 5);
    KS1(wA0, wA1, wA2, wA3, 6);
    KS1(wB0, wB1, wB2, wB3, 7);
    #undef WL1
    #undef KS1

    // f2 prologue: 6 W loads in flight before the H barrier
    const unsigned short* Wp2 = Wf2 + (size_t)(w * 16 + lm) * 1024 + 8 * lg;
    bf16x8 fa, fb, fc, fd, fe, ff, fg, fh;
    #define WL2(d0, ks_) d0 = *(const bf16x8*)(Wp2 + (ks_) * 32)
    WL2(fa, 0); WL2(fb, 1); WL2(fc, 2); WL2(fd, 3); WL2(fe, 4); WL2(ff, 5);

    // f1 epilogue: silu + pack into swizzled H
    {
        int hb = w >> 2;
        #pragma unroll
        for (int nf = 0; nf < 2; nf++) {
            int n = nf * 16 + lm;
            #pragma unroll
            for (int q = 0; q < 4; q++) {
                unsigned long long pk = 0;
                #pragma unroll
                for (int r = 0; r < 4; r++) {
                    int o1 = w * 64 + q * 16 + 4 * lg + r;
                    float v = acc[q][nf][r] + f1b[o1];
                    v = v / (1.f + __expf(-v));
                    pk |= (unsigned long long)f2bf(v) << (16 * r);
                }
                int G = (w & 3) * 8 + q * 2 + (lg >> 1);
                int slot = G ^ (n & 7);
                *(unsigned long long*)&H[hb][(n * 32 + slot) * 8 + 4 * (lg & 1)] = pk;
            }
        }
    }
    __syncthreads();

    f32x4 ac2[2] = {};
    #define KS2(e0, g_) do {                                               \
        int slot = (((g_) & 7) * 4 + lg) ^ m8;                             \
        const unsigned short* Hp = H[(g_) >> 3];                           \
        _Pragma("unroll")                                                  \
        for (int nf = 0; nf < 2; nf++) {                                   \
            bf16x8 xf = *(const bf16x8*)&Hp[((nf * 16 + lm) * 32 + slot) * 8]; \
            ac2[nf] = MFMA(e0, xf, ac2[nf]);                               \
        }                                                                  \
    } while (0)
    // 8-name rotation, 6-step lookahead
    WL2(fg, 6);  KS2(fa, 0);
    WL2(fh, 7);  KS2(fb, 1);
    WL2(fa, 8);  KS2(fc, 2);
    WL2(fb, 9);  KS2(fd, 3);
    WL2(fc, 10); KS2(fe, 4);
    WL2(fd, 11); KS2(ff, 5);
    WL2(fe, 12); KS2(fg, 6);
    WL2(ff, 13); KS2(fh, 7);
    WL2(fg, 14); KS2(fa, 8);
    WL2(fh, 15); KS2(fb, 9);
    WL2(fa, 16); KS2(fc, 10);
    WL2(fb, 17); KS2(fd, 11);
    WL2(fc, 18); KS2(fe, 12);
    WL2(fd, 19); KS2(ff, 13);
    WL2(fe, 20); KS2(fg, 14);
    WL2(ff, 21); KS2(fh, 15);
    WL2(fg, 22); KS2(fa, 16);
    WL2(fh, 23); KS2(fb, 17);
    WL2(fa, 24); KS2(fc, 18);
    WL2(fb, 25); KS2(fd, 19);
    WL2(fc, 26); KS2(fe, 20);
    WL2(fd, 27); KS2(ff, 21);
    WL2(fe, 28); KS2(fg, 22);
    WL2(ff, 29); KS2(fh, 23);
    WL2(fg, 30); KS2(fa, 24);
    WL2(fh, 31); KS2(fb, 25);
    KS2(fc, 26);
    KS2(fd, 27);
    KS2(fe, 28);
    KS2(ff, 29);
    KS2(fg, 30);
    KS2(fh, 31);
    #undef WL2
    #undef KS2

    float gm = gamma[0];
    #pragma unroll
    for (int nf = 0; nf < 2; nf++) {
        int n = nb * 32 + nf * 16 + lm;
        #pragma unroll
        for (int r = 0; r < 4; r++) {
            int o = w * 16 + 4 * lg + r;
            size_t idx = ((size_t)b * Cch + o) * Nsp + n;
            out[idx] = bf2f(x2[idx]) + gm * (ac2[nf][r] + f2b[o]);
        }
    }
}

// ---------- attention v12: 4-buffer KV, 2-tile-ahead issue, 16 q-rows/warp ----------
__global__ __launch_bounds__(256) void attn_mfma8(const unsigned short* __restrict__ qk,
                                                  const unsigned short* __restrict__ v,
                                                  unsigned short* __restrict__ Opart,
                                                  float* __restrict__ lpart) {
    int L = blockIdx.x;
    int xcd = L & 7, jj = L >> 3;            // 1024 blocks: 8 XCDs x 128
    int g = xcd * 4 + (jj >> 5);             // (b,h) 0..31
    int m = jj & 31;                         // (ib,sp) 0..31
    int h = g & 3, b = g >> 2;
    int ib = m & 15, sp = m >> 4;            // ib 0..15, sp {0,1}
    int t = threadIdx.x, w = t >> 6, l = t & 63, lg = l >> 4, lm = l & 15;
    __shared__ unsigned short KVs[4][4096];
    __shared__ unsigned short P[4][16][36];
    int i0 = ib * 64 + w * 16;
    int j0 = sp * 512;
    const unsigned short* qb = qk + ((size_t)b * Nsp + i0 + lm) * 512 + h * 64 + 8 * lg;
    bf16x8 qf00 = *(const bf16x8*)(qb);
    bf16x8 qf01 = *(const bf16x8*)(qb + 32);

    const unsigned short *gs0, *gs1;
    int lo0, lo1;
    size_t gstep;
    if (t < 128) {
        int c = 2 * t;
        int r = c >> 3, s = c & 7, swr = r & 7;
        const unsigned short* rowp = qk + ((size_t)b * Nsp + j0 + r) * 512 + 256 + h * 64;
        gs0 = rowp + ((s ^ swr) * 8);
        gs1 = rowp + (((s + 1) ^ swr) * 8);
        lo0 = c * 8; lo1 = lo0 + 8;
        gstep = (size_t)32 * 512;
    } else {
        int c = 2 * (t - 128);
        int d = c >> 2, s = c & 3, swd = d & 3;
        const unsigned short* rowp = v + ((size_t)b * Cch + h * 64 + d) * Nsp + j0;
        gs0 = rowp + ((s ^ swd) * 8);
        gs1 = rowp + (((s + 1) ^ swd) * 8);
        lo0 = 2048 + c * 8; lo1 = lo0 + 8;
        gstep = 32;
    }
    int cA = (lg ^ (lm & 7)) * 8;
    int cB = ((4 + lg) ^ (lm & 7)) * 8;
    int cV = (lg ^ (lm & 3)) * 8;

    f32x4 O00 = {}, O01 = {}, O02 = {}, O03 = {};
    float ls0 = 0.f;
    bf16x8 sA0, sA1, sB0, sB1;   // two staging sets

    #define ISSUE0(tile) do { sA0 = *(const bf16x8*)(gs0 + (size_t)(tile) * gstep); \
                              sA1 = *(const bf16x8*)(gs1 + (size_t)(tile) * gstep); } while (0)
    #define ISSUE1(tile) do { sB0 = *(const bf16x8*)(gs0 + (size_t)(tile) * gstep); \
                              sB1 = *(const bf16x8*)(gs1 + (size_t)(tile) * gstep); } while (0)
    #define WRITE0(bu) do { *(bf16x8*)&KVs[bu][lo0] = sA0; \
                            *(bf16x8*)&KVs[bu][lo1] = sA1; } while (0)
    #define WRITE1(bu) do { *(bf16x8*)&KVs[bu][lo0] = sB0; \
                            *(bf16x8*)&KVs[bu][lo1] = sB1; } while (0)
    #define QKC8(bu) do {                                                         \
        const unsigned short* Ka = KVs[bu] + lm * 64;                             \
        const unsigned short* Kc = KVs[bu] + (16 + lm) * 64;                      \
        bf16x8 k00 = *(const bf16x8*)(Ka + cA);                                   \
        bf16x8 k01 = *(const bf16x8*)(Ka + cB);                                   \
        bf16x8 k10 = *(const bf16x8*)(Kc + cA);                                   \
        bf16x8 k11 = *(const bf16x8*)(Kc + cB);                                   \
        f32x4 s00 = {}, s10 = {};                                                 \
        s00 = MFMA(k00, qf00, s00); s00 = MFMA(k01, qf01, s00);                   \
        s10 = MFMA(k10, qf00, s10); s10 = MFMA(k11, qf01, s10);                   \
        float p0, p1, p2, p3; uint2 pk;                                           \
        p0 = exp2f(s00[0]); p1 = exp2f(s00[1]); p2 = exp2f(s00[2]); p3 = exp2f(s00[3]); \
        ls0 += (p0 + p1) + (p2 + p3);                                             \
        pk.x = cvtpk(p0, p1); pk.y = cvtpk(p2, p3);                               \
        *(uint2*)&P[w][lm][4 * lg] = pk;                                          \
        p0 = exp2f(s10[0]); p1 = exp2f(s10[1]); p2 = exp2f(s10[2]); p3 = exp2f(s10[3]); \
        ls0 += (p0 + p1) + (p2 + p3);                                             \
        pk.x = cvtpk(p0, p1); pk.y = cvtpk(p2, p3);                               \
        *(uint2*)&P[w][lm][16 + 4 * lg] = pk;                                     \
    } while (0)
    #define PVC8(bu) do {                                                         \
        bf16x8 pa0 = *(const bf16x8*)&P[w][lm][8 * lg];                           \
        const unsigned short* Vl = KVs[bu] + 2048;                                \
        bf16x8 v0 = *(const bf16x8*)(Vl + lm * 32 + cV);                          \
        bf16x8 v1 = *(const bf16x8*)(Vl + (16 + lm) * 32 + cV);                   \
        bf16x8 v2 = *(const bf16x8*)(Vl + (32 + lm) * 32 + cV);                   \
        bf16x8 v3 = *(const bf16x8*)(Vl + (48 + lm) * 32 + cV);                   \
        O00 = MFMA(v0, pa0, O00);                                                 \
        O01 = MFMA(v1, pa0, O01);                                                 \
        O02 = MFMA(v2, pa0, O02);                                                 \
        O03 = MFMA(v3, pa0, O03);                                                 \
    } while (0)

    // prologue
    ISSUE0(0); WRITE0(0); __syncthreads();
    ISSUE1(1);
    QKC8(0);                 // P <- tile0
    WRITE1(1);
    __syncthreads();
    ISSUE0(2);               // tile2 in set0 (written at tt=1)
    // steady state: at iter tt: issue tile tt+2 into set tt&1 (freed at tt-1);
    // PV reads buf (tt-1)%4; QK reads buf tt%4; write tile tt+1 (set (tt+1)&1,
    // issued at iter tt-1) into buf (tt+1)%4 — its prior readers (QK tt-3, PV
    // tt-2) are >=2 barriers upstream.
    // tt=1
    ISSUE1(3);  PVC8(0); QKC8(1); WRITE0(2); __syncthreads();
    // tt=2
    ISSUE0(4);  PVC8(1); QKC8(2); WRITE1(3); __syncthreads();
    // tt=3
    ISSUE1(5);  PVC8(2); QKC8(3); WRITE0(0); __syncthreads();
    // tt=4
    ISSUE0(6);  PVC8(3); QKC8(0); WRITE1(1); __syncthreads();
    // tt=5
    ISSUE1(7);  PVC8(0); QKC8(1); WRITE0(2); __syncthreads();
    // tt=6
    ISSUE0(8);  PVC8(1); QKC8(2); WRITE1(3); __syncthreads();
    // tt=7
    ISSUE1(9);  PVC8(2); QKC8(3); WRITE0(0); __syncthreads();
    // tt=8
    ISSUE0(10); PVC8(3); QKC8(0); WRITE1(1); __syncthreads();
    // tt=9
    ISSUE1(11); PVC8(0); QKC8(1); WRITE0(2); __syncthreads();
    // tt=10
    ISSUE0(12); PVC8(1); QKC8(2); WRITE1(3); __syncthreads();
    // tt=11
    ISSUE1(13); PVC8(2); QKC8(3); WRITE0(0); __syncthreads();
    // tt=12
    ISSUE0(14); PVC8(3); QKC8(0); WRITE1(1); __syncthreads();
    // tt=13
    ISSUE1(15); PVC8(0); QKC8(1); WRITE0(2); __syncthreads();
    // tt=14 (no issue; write tile15 from set1)
    PVC8(1); QKC8(2); WRITE1(3); __syncthreads();
    // tt=15 (no write)
    PVC8(2); QKC8(3);
    // final
    PVC8(3);
    #undef ISSUE0
    #undef ISSUE1
    #undef WRITE0
    #undef WRITE1
    #undef QKC8
    #undef PVC8

    ls0 += __shfl_xor(ls0, 16); ls0 += __shfl_xor(ls0, 32);
    if (lg == 0) {
        float* lp = lpart + (((size_t)sp * Bsz + b) * NHd + h) * Nsp + i0 + lm;
        lp[0] = ls0;
    }
    unsigned short* ob0 = Opart + (((size_t)sp * Bsz + b) * Nsp + i0 + lm) * Cch + h * 64 + 4 * lg;
    uint2 pk;
    #define STO(dt, Oa) \
        pk.x = cvtpk(Oa[0], Oa[1]); pk.y = cvtpk(Oa[2], Oa[3]); \
        *(uint2*)(ob0 + dt * 16) = pk;
    STO(0, O00) STO(1, O01) STO(2, O02) STO(3, O03)
    #undef STO
}

extern "C" void kernel_launch(void* const* d_in, const int* in_sizes, int n_in,
                              void* d_out, int out_size, void* d_ws, size_t ws_size,
                              hipStream_t stream) {
    const float* x      = (const float*)d_in[0];
    const float* qkv_w  = (const float*)d_in[1];
    const float* uh_w   = (const float*)d_in[2];
    const float* uh_b   = (const float*)d_in[3];
    const float* n1_w   = (const float*)d_in[4];
    const float* n1_b   = (const float*)d_in[5];
    const float* n2_w   = (const float*)d_in[6];
    const float* n2_b   = (const float*)d_in[7];
    const float* f1_w   = (const float*)d_in[8];
    const float* f1_b   = (const float*)d_in[9];
    const float* f2_w   = (const float*)d_in[10];
    const float* f2_b   = (const float*)d_in[11];
    const float* g_attn = (const float*)d_in[12];
    const float* g_ffn  = (const float*)d_in[13];
    float* out = (float*)d_out;
    char* ws = (char*)d_ws;

    float*          part1   = (float*)(ws + 1024);
    float*          part2   = (float*)(ws + 5120);
    unsigned short* wbf     = (unsigned short*)(ws + 16384);
    float*          lpart   = (float*)(ws + 2097152);
    unsigned short* qk_cl   = (unsigned short*)(ws + 6291456);
    unsigned short* vbuf    = (unsigned short*)(ws + 14680064);
    unsigned short* x2cl    = (unsigned short*)(ws + 14680064);  // reuses vbuf after attn
    unsigned short* Opart   = (unsigned short*)(ws + 23068672);  // 2 splits x 4MB
    unsigned short* x2rm    = (unsigned short*)(ws + 50331648);  // x2, channel-first bf16

    unsigned short* wbf_qkv = wbf;
    unsigned short* wbf_uh  = wbf + 196608;
    unsigned short* wbf_f1  = wbf + 262144;
    unsigned short* wbf_f2  = wbf + 524288;

    wconv_gn<<<3584, 256, 0, stream>>>(qkv_w, uh_w, f1_w, f2_w, wbf, x, part1);

    // --- attention branch (GN1 fused into qkv staging, xmode=3) ---
    gemm_lds<256, 256, 2><<<dim3(32, 3, Bsz), 256, 0, stream>>>(wbf_qkv,
        (const unsigned short*)x, 0, 3, 3,
        qk_cl, 512, 0, vbuf, nullptr, x, nullptr, nullptr, nullptr, nullptr,
        part1, n1_w, n1_b);
    attn_mfma8<<<1024, 256, 0, stream>>>(qk_cl, vbuf, Opart, lpart);
    // uh GEMM: fused 2-split combine (xmode=2); x2 stored bf16 CF (orm) + bf16 CL (x2cl)
    gemm_lds<256, 256, 1><<<dim3(64, 1, Bsz), 256, 0, stream>>>(wbf_uh, Opart, 2, 0, 2,
        nullptr, 0, 0, x2rm, nullptr, x, x2cl, g_attn, uh_b, part2,
        lpart, nullptr, nullptr);

    // --- FFN branch: single fused kernel, bf16 x2 residual ---
    ffn_fused<<<dim3(32, 1, Bsz), 1024, 0, stream>>>(wbf_f1, wbf_f2, x2cl,
        part2, n2_w, n2_b, f1_b, f2_b, g_ffn, x2rm, out);
}